// Round 1
// baseline (148.940 us; speedup 1.0000x reference)
//
#include <hip/hip_runtime.h>
#include <hip/hip_bf16.h>

typedef __bf16 bf16_t;
typedef bf16_t bf16x8 __attribute__((ext_vector_type(8)));
typedef float f32x4 __attribute__((ext_vector_type(4)));

#define NHEADS 16
#define DFEAT 64
#define DCOORD 8
#define SEQ 2048
#define QBLK 64
#define KVBLK 64
#define KSTR 104   // K' LDS row stride (bf16 elems): 96 used + pad -> conflict-free b128 reads
#define VSTR 72    // V^T LDS row stride
#define PSTR 72    // P LDS row stride

union Bf8 { bf16x8 v; __hip_bfloat16 e[8]; };

__global__ __launch_bounds__(256)
void stfa_kernel(const float* __restrict__ qf, const float* __restrict__ kf,
                 const float* __restrict__ qc, const float* __restrict__ kc,
                 const float* __restrict__ vv, const float* __restrict__ alpha,
                 float* __restrict__ out)
{
    __shared__ __align__(16) __hip_bfloat16 Klds[KVBLK * KSTR];
    __shared__ __align__(16) __hip_bfloat16 Vlds[DFEAT * VSTR];   // transposed: [d][s]
    __shared__ __align__(16) __hip_bfloat16 Plds[4 * 16 * PSTR];

    const int tid  = threadIdx.x;
    const int wave = tid >> 6;
    const int lane = tid & 63;
    const int lr   = lane & 15;   // row-within-16 (A) / col (B,C/D)
    const int lg   = lane >> 4;   // k-group 0..3

    const int blk   = blockIdx.x;
    const int qtile = blk & 31;
    const int h     = (blk >> 5) & 15;
    const int b     = blk >> 9;

    // Zero entire K tile once: cols 72..95 (pad) stay zero for all iterations.
    for (int i = tid; i < KVBLK * KSTR; i += 256) Klds[i] = __float2bfloat16(0.0f);

    const float a_h      = alpha[h];
    const float LOG2E    = 1.4426950408889634f;
    const float qf_scale = 0.125f * LOG2E;                  // 1/sqrt(64) * log2(e)
    const float qc_scale = a_h * 0.35355339059327373f * LOG2E; // alpha/sqrt(8) * log2(e)

    // ---- Load Q' fragments (wave owns rows qtile*64 + wave*16 .. +15) ----
    const int qrow = qtile * QBLK + wave * 16 + lr;
    const float* qf_p = qf + ((long)b * SEQ + qrow) * (NHEADS * DFEAT) + h * DFEAT;
    const float* qc_p = qc + ((long)b * SEQ + qrow) * (NHEADS * DCOORD) + h * DCOORD;

    bf16x8 qfrag[3];
    #pragma unroll
    for (int st = 0; st < 2; ++st) {
        const float* p = qf_p + st * 32 + lg * 8;
        float4 f0 = *(const float4*)p;
        float4 f1 = *(const float4*)(p + 4);
        Bf8 q;
        q.e[0] = __float2bfloat16(f0.x * qf_scale); q.e[1] = __float2bfloat16(f0.y * qf_scale);
        q.e[2] = __float2bfloat16(f0.z * qf_scale); q.e[3] = __float2bfloat16(f0.w * qf_scale);
        q.e[4] = __float2bfloat16(f1.x * qf_scale); q.e[5] = __float2bfloat16(f1.y * qf_scale);
        q.e[6] = __float2bfloat16(f1.z * qf_scale); q.e[7] = __float2bfloat16(f1.w * qf_scale);
        qfrag[st] = q.v;
    }
    {
        Bf8 q;
        #pragma unroll
        for (int i = 0; i < 8; ++i) q.e[i] = __float2bfloat16(0.0f);
        if (lg == 0) {
            float4 c0 = *(const float4*)qc_p;
            float4 c1 = *(const float4*)(qc_p + 4);
            q.e[0] = __float2bfloat16(c0.x * qc_scale); q.e[1] = __float2bfloat16(c0.y * qc_scale);
            q.e[2] = __float2bfloat16(c0.z * qc_scale); q.e[3] = __float2bfloat16(c0.w * qc_scale);
            q.e[4] = __float2bfloat16(c1.x * qc_scale); q.e[5] = __float2bfloat16(c1.y * qc_scale);
            q.e[6] = __float2bfloat16(c1.z * qc_scale); q.e[7] = __float2bfloat16(c1.w * qc_scale);
        }
        qfrag[2] = q.v;
    }

    const float* kf_b = kf + (long)b * SEQ * (NHEADS * DFEAT)  + h * DFEAT;
    const float* kc_b = kc + (long)b * SEQ * (NHEADS * DCOORD) + h * DCOORD;
    const float* v_b  = vv + (long)b * SEQ * (NHEADS * DFEAT)  + h * DFEAT;

    f32x4 oacc[4];
    #pragma unroll
    for (int ct = 0; ct < 4; ++ct) { oacc[ct][0]=0.f; oacc[ct][1]=0.f; oacc[ct][2]=0.f; oacc[ct][3]=0.f; }
    float m_r[4], l_r[4];
    #pragma unroll
    for (int j = 0; j < 4; ++j) { m_r[j] = -3.0e38f; l_r[j] = 0.f; }

    __syncthreads();  // Klds zero visible

    for (int s0 = 0; s0 < SEQ; s0 += KVBLK) {
        // ---- stage K' feat: thread -> (srow = tid>>2, 16 feat dims) ----
        {
            const int srow = tid >> 2, ch = tid & 3;
            const float* p = kf_b + (long)(s0 + srow) * (NHEADS * DFEAT) + ch * 16;
            float4 f0 = ((const float4*)p)[0];
            float4 f1 = ((const float4*)p)[1];
            float4 f2 = ((const float4*)p)[2];
            float4 f3 = ((const float4*)p)[3];
            Bf8 w0, w1;
            w0.e[0]=__float2bfloat16(f0.x); w0.e[1]=__float2bfloat16(f0.y);
            w0.e[2]=__float2bfloat16(f0.z); w0.e[3]=__float2bfloat16(f0.w);
            w0.e[4]=__float2bfloat16(f1.x); w0.e[5]=__float2bfloat16(f1.y);
            w0.e[6]=__float2bfloat16(f1.z); w0.e[7]=__float2bfloat16(f1.w);
            w1.e[0]=__float2bfloat16(f2.x); w1.e[1]=__float2bfloat16(f2.y);
            w1.e[2]=__float2bfloat16(f2.z); w1.e[3]=__float2bfloat16(f2.w);
            w1.e[4]=__float2bfloat16(f3.x); w1.e[5]=__float2bfloat16(f3.y);
            w1.e[6]=__float2bfloat16(f3.z); w1.e[7]=__float2bfloat16(f3.w);
            *(bf16x8*)&Klds[srow * KSTR + ch * 16]     = w0.v;
            *(bf16x8*)&Klds[srow * KSTR + ch * 16 + 8] = w1.v;
        }
        // ---- stage K' coord: 2 dims/thread ----
        {
            const int srow = tid >> 2, cp = (tid & 3) * 2;
            const float* p = kc_b + (long)(s0 + srow) * (NHEADS * DCOORD) + cp;
            float2 c = *(const float2*)p;
            Klds[srow * KSTR + DFEAT + cp]     = __float2bfloat16(c.x);
            Klds[srow * KSTR + DFEAT + cp + 1] = __float2bfloat16(c.y);
        }
        // ---- stage V transposed: thread -> (srow = tid&63, 16 d dims) ----
        {
            const int srow = tid & 63, d0 = (tid >> 6) * 16;
            const float* p = v_b + (long)(s0 + srow) * (NHEADS * DFEAT) + d0;
            #pragma unroll
            for (int c4 = 0; c4 < 4; ++c4) {
                float4 f = ((const float4*)p)[c4];
                Vlds[(d0 + c4 * 4 + 0) * VSTR + srow] = __float2bfloat16(f.x);
                Vlds[(d0 + c4 * 4 + 1) * VSTR + srow] = __float2bfloat16(f.y);
                Vlds[(d0 + c4 * 4 + 2) * VSTR + srow] = __float2bfloat16(f.z);
                Vlds[(d0 + c4 * 4 + 3) * VSTR + srow] = __float2bfloat16(f.w);
            }
        }
        __syncthreads();

        // ---- QK'^T : 4 col-tiles x 3 k-steps ----
        f32x4 sacc[4];
        #pragma unroll
        for (int ct = 0; ct < 4; ++ct) { sacc[ct][0]=0.f; sacc[ct][1]=0.f; sacc[ct][2]=0.f; sacc[ct][3]=0.f; }
        #pragma unroll
        for (int ct = 0; ct < 4; ++ct) {
            #pragma unroll
            for (int st = 0; st < 3; ++st) {
                bf16x8 kfrag = *(const bf16x8*)&Klds[(ct * 16 + lr) * KSTR + st * 32 + lg * 8];
                sacc[ct] = __builtin_amdgcn_mfma_f32_16x16x32_bf16(qfrag[st], kfrag, sacc[ct], 0, 0, 0);
            }
        }

        // ---- online softmax (exp2 domain; scores already scaled by log2e) ----
        float rs[4];
        #pragma unroll
        for (int j = 0; j < 4; ++j) {
            float mx = fmaxf(fmaxf(sacc[0][j], sacc[1][j]), fmaxf(sacc[2][j], sacc[3][j]));
            mx = fmaxf(mx, __shfl_xor(mx, 1));
            mx = fmaxf(mx, __shfl_xor(mx, 2));
            mx = fmaxf(mx, __shfl_xor(mx, 4));
            mx = fmaxf(mx, __shfl_xor(mx, 8));
            float nm = fmaxf(m_r[j], mx);
            rs[j] = __builtin_amdgcn_exp2f(m_r[j] - nm);
            m_r[j] = nm;
        }
        __hip_bfloat16* myP = Plds + wave * 16 * PSTR;
        #pragma unroll
        for (int j = 0; j < 4; ++j) {
            float p0 = __builtin_amdgcn_exp2f(sacc[0][j] - m_r[j]);
            float p1 = __builtin_amdgcn_exp2f(sacc[1][j] - m_r[j]);
            float p2 = __builtin_amdgcn_exp2f(sacc[2][j] - m_r[j]);
            float p3 = __builtin_amdgcn_exp2f(sacc[3][j] - m_r[j]);
            const int r = lg * 4 + j;
            myP[r * PSTR +  0 + lr] = __float2bfloat16(p0);
            myP[r * PSTR + 16 + lr] = __float2bfloat16(p1);
            myP[r * PSTR + 32 + lr] = __float2bfloat16(p2);
            myP[r * PSTR + 48 + lr] = __float2bfloat16(p3);
            float sum = p0 + p1 + p2 + p3;
            sum += __shfl_xor(sum, 1);
            sum += __shfl_xor(sum, 2);
            sum += __shfl_xor(sum, 4);
            sum += __shfl_xor(sum, 8);
            l_r[j] = l_r[j] * rs[j] + sum;
            oacc[0][j] *= rs[j]; oacc[1][j] *= rs[j];
            oacc[2][j] *= rs[j]; oacc[3][j] *= rs[j];
        }

        // ---- PV : P(16x64) * V(64x64); P read back from own-wave LDS (no barrier needed) ----
        #pragma unroll
        for (int kk = 0; kk < 2; ++kk) {
            bf16x8 pfrag = *(const bf16x8*)&myP[lr * PSTR + kk * 32 + lg * 8];
            #pragma unroll
            for (int ct = 0; ct < 4; ++ct) {
                bf16x8 vfrag = *(const bf16x8*)&Vlds[(ct * 16 + lr) * VSTR + kk * 32 + lg * 8];
                oacc[ct] = __builtin_amdgcn_mfma_f32_16x16x32_bf16(pfrag, vfrag, oacc[ct], 0, 0, 0);
            }
        }
        __syncthreads();  // protect Klds/Vlds before next stage
    }

    // ---- epilogue: normalize and store fp32 ----
    #pragma unroll
    for (int j = 0; j < 4; ++j) {
        const float invl = 1.0f / l_r[j];
        const int q = qtile * QBLK + wave * 16 + lg * 4 + j;
        float* op = out + ((long)b * SEQ + q) * (NHEADS * DFEAT) + h * DFEAT;
        op[ 0 + lr] = oacc[0][j] * invl;
        op[16 + lr] = oacc[1][j] * invl;
        op[32 + lr] = oacc[2][j] * invl;
        op[48 + lr] = oacc[3][j] * invl;
    }
}

extern "C" void kernel_launch(void* const* d_in, const int* in_sizes, int n_in,
                              void* d_out, int out_size, void* d_ws, size_t ws_size,
                              hipStream_t stream) {
    const float* qf    = (const float*)d_in[0];
    const float* kf    = (const float*)d_in[1];
    const float* qc    = (const float*)d_in[2];
    const float* kc    = (const float*)d_in[3];
    const float* vv    = (const float*)d_in[4];
    const float* alpha = (const float*)d_in[5];
    float* out = (float*)d_out;

    const int B = 2;
    const int nblocks = B * NHEADS * (SEQ / QBLK);  // 2*16*32 = 1024
    stfa_kernel<<<nblocks, 256, 0, stream>>>(qf, kf, qc, kc, vv, alpha, out);
}